// Round 14
// baseline (184.453 us; speedup 1.0000x reference)
//
#include <hip/hip_runtime.h>
#include <hip/hip_bf16.h>

#define EPS 1e-8f

using short8 = __attribute__((ext_vector_type(8))) short;
using f32x16 = __attribute__((ext_vector_type(16))) float;
typedef unsigned short u16;

#define BARRIER() do { __builtin_amdgcn_s_barrier(); \
                       asm volatile("" ::: "memory"); } while (0)
#define LGKM0() asm volatile("s_waitcnt lgkmcnt(0)" ::: "memory")

__device__ __forceinline__ u16 f2bf(float f) {
    union { float f; unsigned u; } v; v.f = f;
    unsigned u = v.u;
    return (u16)((u + 0x7FFFu + ((u >> 16) & 1u)) >> 16);
}

// ---------------- kernel 1: style[b][i] = dot(w[b], affine_w[i]) + affine_b[i] + 1
__global__ void style_kernel(const float* __restrict__ w,        // [8][512]
                             const float* __restrict__ affine_w, // [256][512]
                             const float* __restrict__ affine_b, // [256]
                             float* __restrict__ style) {        // [8][256]
    int b = blockIdx.x;
    int i = threadIdx.x;
    __shared__ float wb[512];
    for (int z = threadIdx.x; z < 512; z += 256) wb[z] = w[b * 512 + z];
    __syncthreads();
    const float* aw = affine_w + i * 512;
    float acc = 0.f;
#pragma unroll 4
    for (int z = 0; z < 512; z += 4) {
        float4 a4 = *reinterpret_cast<const float4*>(aw + z);
        acc += a4.x * wb[z] + a4.y * wb[z + 1] + a4.z * wb[z + 2] + a4.w * wb[z + 3];
    }
    style[b * 256 + i] = acc + affine_b[i] + 1.0f;
}

// ---------------- kernel 2: modulate + demodulate, pack bf16 weights
// wgt layout: bf16 [b][t(9)][g(32)][o(256)][j(8)], ic = g*8 + j
__global__ void modw_kernel(const float* __restrict__ weight, // [256][256][3][3]
                            const float* __restrict__ style,  // [8][256]
                            u16* __restrict__ wgt) {
    int b = blockIdx.x >> 8;
    int o = blockIdx.x & 255;
    int ic = threadIdx.x; // 256 threads
    float s = style[b * 256 + ic];
    const float* wp = weight + (size_t)(o * 256 + ic) * 9;
    float m[9];
    float ss = 0.f;
#pragma unroll
    for (int t = 0; t < 9; ++t) { m[t] = wp[t] * s; ss += m[t] * m[t]; }
#pragma unroll
    for (int off = 32; off > 0; off >>= 1) ss += __shfl_down(ss, off);
    __shared__ float part[4];
    int lane = threadIdx.x & 63, wid = threadIdx.x >> 6;
    if (lane == 0) part[wid] = ss;
    __syncthreads();
    float denom = rsqrtf(part[0] + part[1] + part[2] + part[3] + EPS);
    int g = ic >> 3, j = ic & 7;
#pragma unroll
    for (int t = 0; t < 9; ++t) {
        size_t idx = ((((size_t)(b * 9 + t) * 32 + g) * 256 + o) << 3) + j;
        wgt[idx] = f2bf(m[t] * denom);
    }
}

// ---------------- kernel 3: fused implicit-GEMM conv, single-row 256-o tile
// block = (b, h): 256 o x 1 row x 128 w, 256 threads (4 waves), 2 blocks/CU.
// Wave wid -> o-quarter wid*64; acc[2][4] (128 AGPR). All waves read the SAME
// B fragments (one output row) -> 3 staged rows (h-1,h,h+1) vs 4, and no ot
// duplication: staging per output element drops 0.5 -> 0.375.
// A: global->VGPR per wave (L2-resident), 1-tap prefetch afC/afN.
// X: fp32 x gathered in-kernel; 24 batch-units (row3 x g4 x half2), 6 per wave,
//    issued at taps 0..5, cvt+ds_written at taps 2..7 (distance-2, no tight tail).
// Chunk boundary: lgkmcnt(0) + barrier. OOB rows never written (zeros persist).
__global__ __launch_bounds__(256, 2) void conv_kernel(
    const float* __restrict__ x,  // [8][256][128][128] fp32
    const u16* __restrict__ wgt,  // [8][9][32][256][8] bf16
    float* __restrict__ out) {    // [8][256][128][128]

    __shared__ __align__(16) u16 Xs[2][3][4][130][8]; // 49920 B [buf][row][g][w130][j8]

    int bid = blockIdx.x;
    int swz = (bid & 7) * 128 + (bid >> 3); // grid 1024 = 8*128, bijective
    int h = swz & 127, b = swz >> 7;

    int tid = threadIdx.x, lane = tid & 63, wid = tid >> 6;
    int l31 = lane & 31, lh = lane >> 5;

    // per-lane A base: (b, t=0, g=lh, o = wid*64 + l31)
    const u16* aBase = wgt + ((size_t)(b * 9) * 32 * 256 +
                              (size_t)(lh * 256 + wid * 64 + l31)) * 8;

    auto loadA = [&](short8 dst[2][2], int c, int t) {
#pragma unroll
        for (int kk = 0; kk < 2; ++kk)
#pragma unroll
            for (int mi = 0; mi < 2; ++mi)
                dst[kk][mi] = *reinterpret_cast<const short8*>(
                    aBase + (size_t)(((t * 32) + c * 4 + kk * 2) * 256 + mi * 32) * 8);
    };
    // unit u (0..23): row=u>>3 (staged row, hr=h+row-1), g=(u>>1)&3, half=u&1
    auto issueX = [&](float* dst, int c1, int u) {
        int row = u >> 3, g = (u >> 1) & 3, half = u & 1;
        int hr = h + row - 1;
        if ((unsigned)hr < 128u) {
            const float* sp = x + (((size_t)(b * 256 + c1 * 32 + g * 8)) * 128 + hr) * 128 +
                              half * 64 + lane;
#pragma unroll
            for (int j = 0; j < 8; ++j) dst[j] = sp[(size_t)j * 16384];
        }
    };
    auto writeX = [&](const float* src, int u, int bx) {
        int row = u >> 3, g = (u >> 1) & 3, half = u & 1;
        int hr = h + row - 1;
        if ((unsigned)hr < 128u) {
            union { u16 u[8]; short8 v; } pk;
#pragma unroll
            for (int j = 0; j < 8; ++j) {
                __hip_bfloat16 hb = __float2bfloat16(src[j]);
                pk.u[j] = reinterpret_cast<u16&>(hb);
            }
            *reinterpret_cast<short8*>(&Xs[bx][row][g][1 + half * 64 + lane][0]) = pk.v;
        }
    };

    // zero both X buffers (borders + OOB rows stay zero forever)
    {
        short8 z = {0, 0, 0, 0, 0, 0, 0, 0};
        short8* p0 = reinterpret_cast<short8*>(&Xs[0][0][0][0][0]);
        for (int i = tid; i < 3120; i += 256) p0[i] = z;
    }
    __syncthreads();

    short8 afC[2][2], afN[2][2];
    // prologue: stage chunk 0 into buf 0 (this wave's 6 units)
    {
        float xg0[6][8];
#pragma unroll
        for (int k = 0; k < 6; ++k) issueX(xg0[k], 0, wid * 6 + k);
#pragma unroll
        for (int k = 0; k < 6; ++k) writeX(xg0[k], wid * 6 + k, 0);
    }
    loadA(afC, 0, 0);
    LGKM0();
    BARRIER();

    f32x16 acc[2][4] = {};
    float xg[2][8]; // ping-pong staging slots (statically indexed under unroll)

    for (int c = 0; c < 8; ++c) {
        int buf = c & 1;
        bool stage = (c < 7);
#pragma unroll
        for (int t = 0; t < 9; ++t) {
            bool lastTap = (c == 7 && t == 8);
            if (!lastTap)
                loadA(afN, t < 8 ? c : c + 1, t < 8 ? t + 1 : 0);
            if (stage) {
                if (t >= 2 && t < 8) writeX(xg[t & 1], wid * 6 + (t - 2), buf ^ 1);
                if (t < 6)           issueX(xg[t & 1], c + 1, wid * 6 + t);
            }

            int kh = t / 3, kw = t - kh * 3;
            short8 bx8[2][4];
#pragma unroll
            for (int kk = 0; kk < 2; ++kk)
#pragma unroll
                for (int ni = 0; ni < 4; ++ni)
                    bx8[kk][ni] = *reinterpret_cast<const short8*>(
                        &Xs[buf][kh][kk * 2 + lh][ni * 32 + l31 + kw][0]);
            __builtin_amdgcn_s_setprio(1);
#pragma unroll
            for (int mi = 0; mi < 2; ++mi)
#pragma unroll
                for (int ni = 0; ni < 4; ++ni)
#pragma unroll
                    for (int kk = 0; kk < 2; ++kk)
                        acc[mi][ni] = __builtin_amdgcn_mfma_f32_32x32x16_bf16(
                            afC[kk][mi], bx8[kk][ni], acc[mi][ni], 0, 0, 0);
            __builtin_amdgcn_s_setprio(0);

            if (!lastTap) {
#pragma unroll
                for (int k2 = 0; k2 < 2; ++k2)
#pragma unroll
                    for (int mi = 0; mi < 2; ++mi)
                        afC[k2][mi] = afN[k2][mi];
            }
        }
        if (c < 7) { LGKM0(); BARRIER(); } // ds_writes of chunk c+1 visible block-wide
    }

    // epilogue: C/D 32x32 layout col=lane&31 (w), row=(reg&3)+8*(reg>>2)+4*(lane>>5) (o)
#pragma unroll
    for (int mi = 0; mi < 2; ++mi) {
        int ob = wid * 64 + mi * 32 + 4 * lh;
#pragma unroll
        for (int ni = 0; ni < 4; ++ni) {
            int w_ = ni * 32 + l31;
#pragma unroll
            for (int reg = 0; reg < 16; ++reg) {
                int o = ob + (reg & 3) + 8 * (reg >> 2);
                out[(((size_t)(b * 256 + o) * 128 + h) * 128) + w_] = acc[mi][ni][reg];
            }
        }
    }
}

extern "C" void kernel_launch(void* const* d_in, const int* in_sizes, int n_in,
                              void* d_out, int out_size, void* d_ws, size_t ws_size,
                              hipStream_t stream) {
    const float* x        = (const float*)d_in[0];
    const float* w        = (const float*)d_in[1];
    const float* weight   = (const float*)d_in[2];
    const float* affine_w = (const float*)d_in[3];
    const float* affine_b = (const float*)d_in[4];
    float* out = (float*)d_out;

    float* style = (float*)d_ws;                                   // 8 KB
    u16* wgt = (u16*)((char*)d_ws + 8192);                         // 9.44 MB

    style_kernel<<<8, 256, 0, stream>>>(w, affine_w, affine_b, style);
    modw_kernel<<<2048, 256, 0, stream>>>(weight, style, wgt);
    conv_kernel<<<1024, 256, 0, stream>>>(x, wgt, out);
}